// Round 1
// baseline (406.119 us; speedup 1.0000x reference)
//
#include <hip/hip_runtime.h>
#include <math.h>

#define BATCH 8
#define CX 256
#define TC 512
#define CIN 768
#define HW_TOT 1024
#define NG 32
#define GSIZE 24          // CIN / NG
#define NH 4
#define CHD 64            // CX / NH
#define QSZ (BATCH*CX*HW_TOT)   // elements per q/k/v buffer = 2,097,152

// ---------------------------------------------------------------------------
// Kernel 1: GroupNorm stats -> per-(b,c) affine scale/shift
// hn[b,c,s] = h[b,c,s]*scale[b,c] + shift[b,c]
// scale = gamma[c]*rsqrt(var+eps), shift = beta[c] - mu*scale
// ---------------------------------------------------------------------------
__global__ __launch_bounds__(256)
void gn_stats_kernel(const float* __restrict__ x, const float* __restrict__ tf,
                     const float* __restrict__ gamma, const float* __restrict__ beta,
                     float* __restrict__ scale, float* __restrict__ shift) {
    const int b = blockIdx.x >> 5;
    const int g = blockIdx.x & 31;
    const int t = threadIdx.x;
    const float* xb = x + (size_t)b * CX * HW_TOT;
    const float* tb = tf + b * TC;

    float s = 0.f, ss = 0.f;
    for (int idx = t; idx < GSIZE * HW_TOT; idx += 256) {
        int cl = idx >> 10;          // channel within group
        int sp = idx & (HW_TOT - 1); // spatial
        int cg = g * GSIZE + cl;
        float v = (cg < CX) ? xb[(size_t)cg * HW_TOT + sp] : tb[cg - CX];
        s += v; ss += v * v;
    }
    __shared__ float red0[256];
    __shared__ float red1[256];
    red0[t] = s; red1[t] = ss;
    __syncthreads();
    for (int off = 128; off > 0; off >>= 1) {
        if (t < off) { red0[t] += red0[t + off]; red1[t] += red1[t + off]; }
        __syncthreads();
    }
    __shared__ float mv[2];
    if (t == 0) {
        const float inv_n = 1.f / (GSIZE * HW_TOT);
        float mean = red0[0] * inv_n;
        float var = red1[0] * inv_n - mean * mean;
        mv[0] = mean;
        mv[1] = rsqrtf(var + 1e-6f);
    }
    __syncthreads();
    if (t < GSIZE) {
        int cg = g * GSIZE + t;
        float sc = gamma[cg] * mv[1];
        scale[b * CIN + cg] = sc;
        shift[b * CIN + cg] = beta[cg] - mv[0] * sc;
    }
}

// ---------------------------------------------------------------------------
// Kernel 2: fused normalize + QKV projection.
// out[b,d,hw] = sum_c (h[b,c,hw]*scale+shift) * W[c,d] + bias[d]
// 64x64 output tile, BK=16, 4x4 micro-tile per thread, 256 threads.
// Grid: (hw tiles=16, d tiles=12 [0-3:W0, 4-7:W1, 8-11:W2], batch=8)
// ---------------------------------------------------------------------------
__global__ __launch_bounds__(256)
void qkv_kernel(const float* __restrict__ x, const float* __restrict__ tf,
                const float* __restrict__ scale, const float* __restrict__ shift,
                const float* __restrict__ W0, const float* __restrict__ b0,
                const float* __restrict__ W1, const float* __restrict__ b1,
                const float* __restrict__ W2, const float* __restrict__ b2,
                float* __restrict__ qkv) {
    const int hw0 = blockIdx.x * 64;
    const int dt  = blockIdx.y;
    const int b   = blockIdx.z;
    const int which = dt >> 2;
    const int col0  = (dt & 3) * 64;
    const float* Wm   = (which == 0) ? W0 : (which == 1) ? W1 : W2;
    const float* bias = (which == 0) ? b0 : (which == 1) ? b1 : b2;
    float* outp = qkv + (size_t)which * QSZ + (size_t)b * CX * HW_TOT;

    __shared__ float Ws[16 * 64];
    __shared__ float Hs[16 * 64];

    const int t = threadIdx.x;
    const int tx = t & 15, ty = t >> 4;
    const float* xb  = x + (size_t)b * CX * HW_TOT;
    const float* tb  = tf + b * TC;
    const float* scb = scale + b * CIN;
    const float* shb = shift + b * CIN;

    float acc[4][4];
    #pragma unroll
    for (int i = 0; i < 4; i++)
        #pragma unroll
        for (int j = 0; j < 4; j++) acc[i][j] = 0.f;

    for (int k0 = 0; k0 < CIN; k0 += 16) {
        int idx = t;
        #pragma unroll
        for (int r = 0; r < 4; r++) {
            int kk = idx >> 6, dl = idx & 63;
            int cg = k0 + kk;
            Ws[kk * 64 + dl] = Wm[(size_t)cg * CX + col0 + dl];
            float v = (cg < CX) ? xb[(size_t)cg * HW_TOT + hw0 + dl] : tb[cg - CX];
            Hs[kk * 64 + dl] = v * scb[cg] + shb[cg];
            idx += 256;
        }
        __syncthreads();
        #pragma unroll
        for (int kk = 0; kk < 16; kk++) {
            float4 a4 = *(const float4*)&Ws[kk * 64 + ty * 4];
            float4 b4 = *(const float4*)&Hs[kk * 64 + tx * 4];
            float av[4] = {a4.x, a4.y, a4.z, a4.w};
            float bv[4] = {b4.x, b4.y, b4.z, b4.w};
            #pragma unroll
            for (int i = 0; i < 4; i++)
                #pragma unroll
                for (int j = 0; j < 4; j++)
                    acc[i][j] = fmaf(av[i], bv[j], acc[i][j]);
        }
        __syncthreads();
    }
    #pragma unroll
    for (int i = 0; i < 4; i++) {
        int dl = ty * 4 + i;
        float bs = bias[col0 + dl];
        float4 o = make_float4(acc[i][0] + bs, acc[i][1] + bs,
                               acc[i][2] + bs, acc[i][3] + bs);
        *(float4*)&outp[(size_t)(col0 + dl) * HW_TOT + hw0 + tx * 4] = o;
    }
}

// ---------------------------------------------------------------------------
// Kernel 3: flash-style attention + residual.
// Per block: one (b,head) x one 64-query tile. K-loop over 16 key tiles.
// S = Q^T K * 0.125, online softmax (rows live in 16-lane shuffle groups),
// P round-trips through LDS (aliased onto K buffer), O += P V.
// Grid: (q tiles=16, b*heads=32), 256 threads.
// ---------------------------------------------------------------------------
__global__ __launch_bounds__(256)
void attn_kernel(const float* __restrict__ qkv, const float* __restrict__ x,
                 float* __restrict__ out) {
    const int qt = blockIdx.x;
    const int bh = blockIdx.y;
    const int b = bh >> 2, h = bh & 3;
    const int hw0 = qt * 64;
    const float* qb = qkv + ((size_t)b * CX + h * CHD) * HW_TOT;
    const float* kb = qb + QSZ;
    const float* vb = qb + (size_t)2 * QSZ;

    __shared__ float Qs[64 * 64];   // [c][qi]
    __shared__ float KP[64 * 68];   // K tile [c][kj], reused as P [qi][kj]
    __shared__ float Vs[64 * 68];   // V tile transposed [kj][c]

    const int t = threadIdx.x;
    const int tx = t & 15, ty = t >> 4;

    for (int idx = t; idx < 4096; idx += 256) {
        int c = idx >> 6, qi = idx & 63;
        Qs[c * 64 + qi] = qb[(size_t)c * HW_TOT + hw0 + qi];
    }

    float m[4], l[4], acc[4][4];
    #pragma unroll
    for (int i = 0; i < 4; i++) {
        m[i] = -1e30f; l[i] = 0.f;
        #pragma unroll
        for (int j = 0; j < 4; j++) acc[i][j] = 0.f;
    }
    __syncthreads();

    for (int j0 = 0; j0 < HW_TOT; j0 += 64) {
        for (int idx = t; idx < 4096; idx += 256) {
            int c = idx >> 6, kj = idx & 63;
            KP[c * 68 + kj] = kb[(size_t)c * HW_TOT + j0 + kj];
            Vs[kj * 68 + c] = vb[(size_t)c * HW_TOT + j0 + kj];
        }
        __syncthreads();

        // S tile: s[i][j], qi = ty*4+i, kj = tx*4+j
        float s[4][4];
        #pragma unroll
        for (int i = 0; i < 4; i++)
            #pragma unroll
            for (int j = 0; j < 4; j++) s[i][j] = 0.f;

        #pragma unroll 8
        for (int c = 0; c < 64; c++) {
            float4 a4 = *(const float4*)&Qs[c * 64 + ty * 4];
            float4 k4 = *(const float4*)&KP[c * 68 + tx * 4];
            float av[4] = {a4.x, a4.y, a4.z, a4.w};
            float bv[4] = {k4.x, k4.y, k4.z, k4.w};
            #pragma unroll
            for (int i = 0; i < 4; i++)
                #pragma unroll
                for (int j = 0; j < 4; j++)
                    s[i][j] = fmaf(av[i], bv[j], s[i][j]);
        }
        #pragma unroll
        for (int i = 0; i < 4; i++)
            #pragma unroll
            for (int j = 0; j < 4; j++) s[i][j] *= 0.125f;

        // online softmax; row qi spans the 16 lanes sharing ty
        #pragma unroll
        for (int i = 0; i < 4; i++) {
            float mx = fmaxf(fmaxf(s[i][0], s[i][1]), fmaxf(s[i][2], s[i][3]));
            #pragma unroll
            for (int d = 1; d < 16; d <<= 1) mx = fmaxf(mx, __shfl_xor(mx, d));
            float mn = fmaxf(m[i], mx);
            float al = __expf(m[i] - mn);
            float rsum = 0.f;
            #pragma unroll
            for (int j = 0; j < 4; j++) {
                float p = __expf(s[i][j] - mn);
                s[i][j] = p; rsum += p;
            }
            #pragma unroll
            for (int d = 1; d < 16; d <<= 1) rsum += __shfl_xor(rsum, d);
            l[i] = l[i] * al + rsum;
            m[i] = mn;
            #pragma unroll
            for (int j = 0; j < 4; j++) acc[i][j] *= al;
        }
        __syncthreads();   // all waves done reading K before P overwrites it
        #pragma unroll
        for (int i = 0; i < 4; i++) {
            float4 p4 = make_float4(s[i][0], s[i][1], s[i][2], s[i][3]);
            *(float4*)&KP[(ty * 4 + i) * 68 + tx * 4] = p4;
        }
        __syncthreads();

        // O += P V : acc[i][jc], qi = ty*4+i, c = tx*4+jc
        #pragma unroll 8
        for (int j = 0; j < 64; j++) {
            float4 v4 = *(const float4*)&Vs[j * 68 + tx * 4];
            float vv[4] = {v4.x, v4.y, v4.z, v4.w};
            float pr[4];
            #pragma unroll
            for (int i = 0; i < 4; i++) pr[i] = KP[(ty * 4 + i) * 68 + j];
            #pragma unroll
            for (int i = 0; i < 4; i++)
                #pragma unroll
                for (int jc = 0; jc < 4; jc++)
                    acc[i][jc] = fmaf(pr[i], vv[jc], acc[i][jc]);
        }
        __syncthreads();
    }

    float rl[4];
    #pragma unroll
    for (int i = 0; i < 4; i++) rl[i] = 1.f / l[i];
    const float* xb = x + ((size_t)b * CX + h * CHD) * HW_TOT;
    float* ob = out + ((size_t)b * CX + h * CHD) * HW_TOT;
    #pragma unroll
    for (int jc = 0; jc < 4; jc++) {
        int c = tx * 4 + jc;
        size_t base = (size_t)c * HW_TOT + hw0 + ty * 4;
        float4 xv = *(const float4*)&xb[base];
        float4 o;
        o.x = xv.x + acc[0][jc] * rl[0];
        o.y = xv.y + acc[1][jc] * rl[1];
        o.z = xv.z + acc[2][jc] * rl[2];
        o.w = xv.w + acc[3][jc] * rl[3];
        *(float4*)&ob[base] = o;
    }
}

// ---------------------------------------------------------------------------
extern "C" void kernel_launch(void* const* d_in, const int* in_sizes, int n_in,
                              void* d_out, int out_size, void* d_ws, size_t ws_size,
                              hipStream_t stream) {
    (void)in_sizes; (void)n_in; (void)out_size; (void)ws_size;
    const float* x     = (const float*)d_in[0];
    const float* tf    = (const float*)d_in[1];
    const float* gamma = (const float*)d_in[2];
    const float* beta  = (const float*)d_in[3];
    const float* W0 = (const float*)d_in[4];
    const float* b0 = (const float*)d_in[5];
    const float* W1 = (const float*)d_in[6];
    const float* b1 = (const float*)d_in[7];
    const float* W2 = (const float*)d_in[8];
    const float* b2 = (const float*)d_in[9];

    float* ws    = (float*)d_ws;
    float* scale = ws;                       // [B][CIN]
    float* shift = ws + BATCH * CIN;         // [B][CIN]
    float* qkv   = ws + 2 * BATCH * CIN;     // q,k,v each QSZ floats

    hipLaunchKernelGGL(gn_stats_kernel, dim3(BATCH * NG), dim3(256), 0, stream,
                       x, tf, gamma, beta, scale, shift);
    hipLaunchKernelGGL(qkv_kernel, dim3(16, 12, BATCH), dim3(256), 0, stream,
                       x, tf, scale, shift, W0, b0, W1, b1, W2, b2, qkv);
    hipLaunchKernelGGL(attn_kernel, dim3(16, 32), dim3(256), 0, stream,
                       qkv, x, (float*)d_out);
}

// Round 2
// 173.314 us; speedup vs baseline: 2.3433x; 2.3433x over previous
//
#include <hip/hip_runtime.h>
#include <math.h>

#define BATCH 8
#define CX 256
#define TC 512
#define CIN 768
#define HW_TOT 1024
#define NH 4
#define CHD 64

typedef __attribute__((ext_vector_type(8))) short short8;
typedef __attribute__((ext_vector_type(4))) float floatx4;

// round-to-nearest-even f32 -> bf16 (bit trick; avoids header type friction)
static __device__ __forceinline__ short f2bf(float f) {
    union { float f; unsigned u; } c; c.f = f;
    unsigned r = (c.u + 0x7fffu + ((c.u >> 16) & 1u)) >> 16;
    return (short)r;
}

// ---------------------------------------------------------------------------
// Kernel 1: GroupNorm stats -> per-(b,c) affine scale/shift (fp32).
// ---------------------------------------------------------------------------
__global__ __launch_bounds__(256)
void gn_stats_kernel(const float* __restrict__ x, const float* __restrict__ tf,
                     const float* __restrict__ gamma, const float* __restrict__ beta,
                     float* __restrict__ scale, float* __restrict__ shift) {
    const int b = blockIdx.x >> 5;
    const int g = blockIdx.x & 31;
    const int t = threadIdx.x;
    const float* xb = x + (size_t)b * CX * HW_TOT;
    const float* tb = tf + b * TC;

    float s = 0.f, ss = 0.f;
    for (int idx = t; idx < 24 * HW_TOT; idx += 256) {
        int cl = idx >> 10;
        int sp = idx & (HW_TOT - 1);
        int cg = g * 24 + cl;
        float v = (cg < CX) ? xb[(size_t)cg * HW_TOT + sp] : tb[cg - CX];
        s += v; ss += v * v;
    }
    __shared__ float red0[256];
    __shared__ float red1[256];
    red0[t] = s; red1[t] = ss;
    __syncthreads();
    for (int off = 128; off > 0; off >>= 1) {
        if (t < off) { red0[t] += red0[t + off]; red1[t] += red1[t + off]; }
        __syncthreads();
    }
    __shared__ float mv[2];
    if (t == 0) {
        const float inv_n = 1.f / (24 * HW_TOT);
        float mean = red0[0] * inv_n;
        float var = red1[0] * inv_n - mean * mean;
        mv[0] = mean;
        mv[1] = rsqrtf(var + 1e-6f);
    }
    __syncthreads();
    if (t < 24) {
        int cg = g * 24 + t;
        float sc = gamma[cg] * mv[1];
        scale[b * CIN + cg] = sc;
        shift[b * CIN + cg] = beta[cg] - mv[0] * sc;
    }
}

// ---------------------------------------------------------------------------
// Kernel 2: W -> Wt bf16 transposed: Wt[dg][c] = W_which[c][d], dg=which*256+d,
// spatial channels only (c<256). Grid (3, 4) x 256.
// ---------------------------------------------------------------------------
__global__ __launch_bounds__(256)
void wt_kernel(const float* __restrict__ W0, const float* __restrict__ W1,
               const float* __restrict__ W2, short* __restrict__ Wt) {
    int dg = blockIdx.x * 256 + threadIdx.x;
    int which = dg >> 8, d = dg & 255;
    const float* Wm = (which == 0) ? W0 : (which == 1) ? W1 : W2;
    int c0base = blockIdx.y * 64;
    for (int c0 = c0base; c0 < c0base + 64; c0 += 8) {
        short8 o;
        #pragma unroll
        for (int i = 0; i < 8; i++) o[i] = f2bf(Wm[(size_t)(c0 + i) * CX + d]);
        *(short8*)(Wt + (size_t)dg * CX + c0) = o;
    }
}

// ---------------------------------------------------------------------------
// Kernel 3: hnT bf16 [b][hw][c<256] = normalize(x) transposed.
// Grid (32, 8) x 256: blockIdx.x covers 256 hw-rows, blockIdx.y a 32-ch slice.
// ---------------------------------------------------------------------------
__global__ __launch_bounds__(256)
void hnt_kernel(const float* __restrict__ x, const float* __restrict__ scale,
                const float* __restrict__ shift, short* __restrict__ hnT) {
    int id = blockIdx.x * 256 + threadIdx.x;     // b*1024 + hw
    int b = id >> 10;
    const float* xb = x + (size_t)b * CX * HW_TOT + (id & 1023);
    const float* scb = scale + b * CIN;
    const float* shb = shift + b * CIN;
    short* outp = hnT + (size_t)id * CX;
    int c0base = blockIdx.y * 32;
    for (int c0 = c0base; c0 < c0base + 32; c0 += 8) {
        short8 o;
        #pragma unroll
        for (int i = 0; i < 8; i++) {
            float v = xb[(size_t)(c0 + i) * HW_TOT];
            o[i] = f2bf(v * scb[c0 + i] + shb[c0 + i]);
        }
        *(short8*)(outp + c0) = o;
    }
}

// ---------------------------------------------------------------------------
// Kernel 4: text contribution tc[b][dg] = sum_{c=256..767} hn_text[b][c]*W[c][d]
// (text features are spatially broadcast -> per-batch constant; removes 2/3 of
// the big GEMM's K). fp32 exact. Grid (8, 12) x 256.
// ---------------------------------------------------------------------------
__global__ __launch_bounds__(256)
void text_kernel(const float* __restrict__ tf, const float* __restrict__ scale,
                 const float* __restrict__ shift,
                 const float* __restrict__ W0, const float* __restrict__ W1,
                 const float* __restrict__ W2, float* __restrict__ tc) {
    int b = blockIdx.x, dt = blockIdx.y;
    int which = dt >> 2, d0 = (dt & 3) * 64;
    const float* Wm = (which == 0) ? W0 : (which == 1) ? W1 : W2;
    __shared__ float hs[TC];
    __shared__ float red[4][64];
    int t = threadIdx.x;
    for (int c = t; c < TC; c += 256)
        hs[c] = tf[b * TC + c] * scale[b * CIN + CX + c] + shift[b * CIN + CX + c];
    __syncthreads();
    int td = t & 63, tq = t >> 6;
    float acc = 0.f;
    const float* wp = Wm + (size_t)(CX + tq * 128) * CX + d0 + td;
    for (int c = 0; c < 128; c++)
        acc = fmaf(hs[tq * 128 + c], wp[(size_t)c * CX], acc);
    red[tq][td] = acc;
    __syncthreads();
    if (t < 64)
        tc[b * CIN + which * CX + d0 + t] = red[0][t] + red[1][t] + red[2][t] + red[3][t];
}

// ---------------------------------------------------------------------------
// Kernel 5: MFMA QKV GEMM over spatial channels (K=256), bf16 in / fp32 acc.
// 128x128 tile, BK=32, 4 waves of 64x64, 16x16x32 MFMA.
// q,k written [b][hw][256]; v written [b][256][1024] (A/B roles swapped).
// Grid (8 hw-tiles, 6 d-tiles, 8 b) x 256.
// ---------------------------------------------------------------------------
__global__ __launch_bounds__(256)
void qkv_gemm(const short* __restrict__ hnT, const short* __restrict__ Wt,
              const float* __restrict__ tc,
              const float* __restrict__ b0, const float* __restrict__ b1,
              const float* __restrict__ b2,
              short* __restrict__ qb, short* __restrict__ kb, short* __restrict__ vb) {
    const int hw0 = blockIdx.x * 128, dt = blockIdx.y, b = blockIdx.z;
    const int dg0 = dt * 128;
    const int which = dt >> 1;
    const bool OV = (which == 2);

    __shared__ short At[128 * 40];   // hnT tile [hw][k], stride 40 (2-way free)
    __shared__ short Bt[128 * 40];   // Wt  tile [d][k]

    const int t = threadIdx.x;
    const int w = t >> 6, l = t & 63;
    const int wm = w >> 1, wn = w & 1;
    const int l15 = l & 15, q = l >> 4;

    const int srow = t >> 1, sch = (t & 1) * 16;
    const short* gA = hnT + (size_t)(b * HW_TOT + hw0 + srow) * CX + sch;
    const short* gB = Wt + (size_t)(dg0 + srow) * CX + sch;
    short* lA = At + srow * 40 + sch;
    short* lB = Bt + srow * 40 + sch;

    floatx4 acc[4][4] = {};
    for (int k0 = 0; k0 < CX; k0 += 32) {
        __syncthreads();
        *(short8*)lA       = *(const short8*)(gA + k0);
        *(short8*)(lA + 8) = *(const short8*)(gA + k0 + 8);
        *(short8*)lB       = *(const short8*)(gB + k0);
        *(short8*)(lB + 8) = *(const short8*)(gB + k0 + 8);
        __syncthreads();
        const short* aBase = OV ? Bt : At;
        const short* bBase = OV ? At : Bt;
        short8 af[4], bf[4];
        #pragma unroll
        for (int mt = 0; mt < 4; mt++)
            af[mt] = *(const short8*)(aBase + (wm * 64 + mt * 16 + l15) * 40 + q * 8);
        #pragma unroll
        for (int nt = 0; nt < 4; nt++)
            bf[nt] = *(const short8*)(bBase + (wn * 64 + nt * 16 + l15) * 40 + q * 8);
        #pragma unroll
        for (int mt = 0; mt < 4; mt++)
            #pragma unroll
            for (int nt = 0; nt < 4; nt++)
                acc[mt][nt] = __builtin_amdgcn_mfma_f32_16x16x32_bf16(
                    af[mt], bf[nt], acc[mt][nt], 0, 0, 0);
    }

    __syncthreads();   // all frag reads done before epilogue clobbers At
    const float* bias = (which == 0) ? b0 : (which == 1) ? b1 : b2;
    short* epi = At + w * (16 * 72);   // per-wave 16x72 staging

    float colAdd[4];
    if (!OV) {
        #pragma unroll
        for (int nt = 0; nt < 4; nt++) {
            int cl = (dt & 1) * 128 + wn * 64 + l15 + nt * 16;
            colAdd[nt] = bias[cl] + tc[b * CIN + which * CX + cl];
        }
    }
    const int row_l = l >> 2, ch = l & 3;
    #pragma unroll
    for (int mt = 0; mt < 4; mt++) {
        #pragma unroll
        for (int rr = 0; rr < 4; rr++) {
            float radd = 0.f;
            if (OV) {
                int rl = (dt & 1) * 128 + wm * 64 + mt * 16 + q * 4 + rr;
                radd = bias[rl] + tc[b * CIN + 2 * CX + rl];
            }
            #pragma unroll
            for (int nt = 0; nt < 4; nt++) {
                float val = acc[mt][nt][rr] + (OV ? radd : colAdd[nt]);
                epi[(q * 4 + rr) * 72 + l15 + nt * 16] = f2bf(val);
            }
        }
        // same-wave readback (compiler inserts lgkmcnt), coalesced store
        short8 v0 = *(const short8*)(epi + row_l * 72 + ch * 16);
        short8 v1 = *(const short8*)(epi + row_l * 72 + ch * 16 + 8);
        if (!OV) {
            short* outp = (which == 0) ? qb : kb;
            size_t off = (size_t)(b * HW_TOT + hw0 + wm * 64 + mt * 16 + row_l) * CX
                       + (dt & 1) * 128 + wn * 64 + ch * 16;
            *(short8*)(outp + off) = v0;
            *(short8*)(outp + off + 8) = v1;
        } else {
            size_t off = (size_t)(b * CX + (dt & 1) * 128 + wm * 64 + mt * 16 + row_l) * HW_TOT
                       + hw0 + wn * 64 + ch * 16;
            *(short8*)(vb + off) = v0;
            *(short8*)(vb + off + 8) = v1;
        }
    }
}

// ---------------------------------------------------------------------------
// Kernel 6: flash attention w/ MFMA + residual.
// Per block: (b,head) x 64-query tile; wave w owns qi rows [w*16, w*16+16).
// S = Q K^T (MFMA), online softmax in C-layout (16-lane shuffle rows),
// P -> LDS (bf16) -> A-layout, O += P V (MFMA). Grid (16, 32) x 256.
// ---------------------------------------------------------------------------
__global__ __launch_bounds__(256)
void attn_kernel(const short* __restrict__ qb, const short* __restrict__ kb,
                 const short* __restrict__ vb, const float* __restrict__ x,
                 float* __restrict__ out) {
    const int qt = blockIdx.x, bh = blockIdx.y;
    const int b = bh >> 2, h = bh & 3;
    const int hw0 = qt * 64;

    __shared__ __align__(16) char smem[4 * 9216];
    short* Qs = (short*)smem;                // [qi][c]  stride 72
    short* Ks = (short*)(smem + 9216);       // [kj][c]  stride 72
    short* Vs = (short*)(smem + 18432);      // [c][kj]  stride 72
    short* Ps = (short*)(smem + 27648);      // [qi][kj] stride 72
    float* Of = (float*)smem;                // epilogue [c][qi] stride 68 (17.4KB, aliases Qs+Ks)

    const int t = threadIdx.x;
    const int w = t >> 6, l = t & 63;
    const int l15 = l & 15, q = l >> 4;
    const int srow = t >> 2, sch = (t & 3) * 16;

    {   // stage Q once
        const short* gq = qb + (size_t)(b * HW_TOT + hw0 + srow) * CX + h * CHD + sch;
        *(short8*)(Qs + srow * 72 + sch)     = *(const short8*)gq;
        *(short8*)(Qs + srow * 72 + sch + 8) = *(const short8*)(gq + 8);
    }
    __syncthreads();
    short8 aq0 = *(const short8*)(Qs + (w * 16 + l15) * 72 + q * 8);
    short8 aq1 = *(const short8*)(Qs + (w * 16 + l15) * 72 + 32 + q * 8);

    floatx4 oacc[4] = {};
    float mrow[4], lrow[4];
    #pragma unroll
    for (int r = 0; r < 4; r++) { mrow[r] = -1e30f; lrow[r] = 0.f; }

    for (int j0 = 0; j0 < HW_TOT; j0 += 64) {
        __syncthreads();   // previous tile's K/V reads complete
        {
            const short* gk = kb + (size_t)(b * HW_TOT + j0 + srow) * CX + h * CHD + sch;
            *(short8*)(Ks + srow * 72 + sch)     = *(const short8*)gk;
            *(short8*)(Ks + srow * 72 + sch + 8) = *(const short8*)(gk + 8);
            const short* gv = vb + (size_t)(b * CX + h * CHD + srow) * HW_TOT + j0 + sch;
            *(short8*)(Vs + srow * 72 + sch)     = *(const short8*)gv;
            *(short8*)(Vs + srow * 72 + sch + 8) = *(const short8*)(gv + 8);
        }
        __syncthreads();

        floatx4 sacc[4] = {};
        #pragma unroll
        for (int nt = 0; nt < 4; nt++) {
            short8 bk0 = *(const short8*)(Ks + (nt * 16 + l15) * 72 + q * 8);
            short8 bk1 = *(const short8*)(Ks + (nt * 16 + l15) * 72 + 32 + q * 8);
            sacc[nt] = __builtin_amdgcn_mfma_f32_16x16x32_bf16(aq0, bk0, sacc[nt], 0, 0, 0);
            sacc[nt] = __builtin_amdgcn_mfma_f32_16x16x32_bf16(aq1, bk1, sacc[nt], 0, 0, 0);
        }

        #pragma unroll
        for (int r = 0; r < 4; r++) {
            float t0 = sacc[0][r] * 0.125f, t1 = sacc[1][r] * 0.125f;
            float t2 = sacc[2][r] * 0.125f, t3 = sacc[3][r] * 0.125f;
            float mx = fmaxf(fmaxf(t0, t1), fmaxf(t2, t3));
            #pragma unroll
            for (int d = 1; d < 16; d <<= 1) mx = fmaxf(mx, __shfl_xor(mx, d));
            float mn = fmaxf(mrow[r], mx);
            float al = __expf(mrow[r] - mn);
            float p0 = __expf(t0 - mn), p1 = __expf(t1 - mn);
            float p2 = __expf(t2 - mn), p3 = __expf(t3 - mn);
            float rs = p0 + p1 + p2 + p3;
            #pragma unroll
            for (int d = 1; d < 16; d <<= 1) rs += __shfl_xor(rs, d);
            lrow[r] = lrow[r] * al + rs;
            mrow[r] = mn;
            #pragma unroll
            for (int nt = 0; nt < 4; nt++) oacc[nt][r] *= al;
            short* pr = Ps + (w * 16 + q * 4 + r) * 72;
            pr[l15]      = f2bf(p0);
            pr[l15 + 16] = f2bf(p1);
            pr[l15 + 32] = f2bf(p2);
            pr[l15 + 48] = f2bf(p3);
        }

        // P rows live within this wave -> no barrier, compiler waits lgkmcnt
        short8 ap0 = *(const short8*)(Ps + (w * 16 + l15) * 72 + q * 8);
        short8 ap1 = *(const short8*)(Ps + (w * 16 + l15) * 72 + 32 + q * 8);
        #pragma unroll
        for (int nt = 0; nt < 4; nt++) {
            short8 bv0 = *(const short8*)(Vs + (nt * 16 + l15) * 72 + q * 8);
            short8 bv1 = *(const short8*)(Vs + (nt * 16 + l15) * 72 + 32 + q * 8);
            oacc[nt] = __builtin_amdgcn_mfma_f32_16x16x32_bf16(ap0, bv0, oacc[nt], 0, 0, 0);
            oacc[nt] = __builtin_amdgcn_mfma_f32_16x16x32_bf16(ap1, bv1, oacc[nt], 0, 0, 0);
        }
    }

    __syncthreads();   // done reading Qs/Ks before Of aliases them
    #pragma unroll
    for (int nt = 0; nt < 4; nt++) {
        #pragma unroll
        for (int r = 0; r < 4; r++)
            Of[(l15 + nt * 16) * 68 + (w * 16 + q * 4 + r)] = oacc[nt][r] / lrow[r];
    }
    __syncthreads();
    {
        const int c = srow;
        const size_t base = (size_t)(b * CX + h * CHD + c) * HW_TOT + hw0 + sch;
        const float* ofp = Of + c * 68 + sch;
        #pragma unroll
        for (int i = 0; i < 16; i += 4) {
            float4 xv = *(const float4*)(x + base + i);
            float4 ov;
            ov.x = ofp[i]     + xv.x;
            ov.y = ofp[i + 1] + xv.y;
            ov.z = ofp[i + 2] + xv.z;
            ov.w = ofp[i + 3] + xv.w;
            *(float4*)(out + base + i) = ov;
        }
    }
}

// ---------------------------------------------------------------------------
extern "C" void kernel_launch(void* const* d_in, const int* in_sizes, int n_in,
                              void* d_out, int out_size, void* d_ws, size_t ws_size,
                              hipStream_t stream) {
    (void)in_sizes; (void)n_in; (void)out_size; (void)ws_size;
    const float* x     = (const float*)d_in[0];
    const float* tf    = (const float*)d_in[1];
    const float* gamma = (const float*)d_in[2];
    const float* beta  = (const float*)d_in[3];
    const float* W0 = (const float*)d_in[4];
    const float* b0 = (const float*)d_in[5];
    const float* W1 = (const float*)d_in[6];
    const float* b1 = (const float*)d_in[7];
    const float* W2 = (const float*)d_in[8];
    const float* b2 = (const float*)d_in[9];

    char* ws = (char*)d_ws;
    float* scale = (float*)(ws);                  // 24576 B
    float* shift = (float*)(ws + 24576);          // 24576 B
    float* tcb   = (float*)(ws + 49152);          // 24576 B
    short* Wt    = (short*)(ws + 73728);          // 393216 B
    short* hnT   = (short*)(ws + 466944);         // 4 MiB
    short* qb    = (short*)(ws + 4661248);        // 4 MiB
    short* kb    = (short*)(ws + 8855552);        // 4 MiB
    short* vb    = (short*)(ws + 13049856);       // 4 MiB  (total 17.2 MB)

    hipLaunchKernelGGL(gn_stats_kernel, dim3(BATCH * 32), dim3(256), 0, stream,
                       x, tf, gamma, beta, scale, shift);
    hipLaunchKernelGGL(wt_kernel, dim3(3, 4), dim3(256), 0, stream, W0, W1, W2, Wt);
    hipLaunchKernelGGL(hnt_kernel, dim3(32, 8), dim3(256), 0, stream, x, scale, shift, hnT);
    hipLaunchKernelGGL(text_kernel, dim3(BATCH, 12), dim3(256), 0, stream,
                       tf, scale, shift, W0, W1, W2, tcb);
    hipLaunchKernelGGL(qkv_gemm, dim3(8, 6, BATCH), dim3(256), 0, stream,
                       hnT, Wt, tcb, b0, b1, b2, qb, kb, vb);
    hipLaunchKernelGGL(attn_kernel, dim3(16, 32), dim3(256), 0, stream,
                       qb, kb, vb, x, (float*)d_out);
}

// Round 3
// 135.485 us; speedup vs baseline: 2.9975x; 1.2792x over previous
//
#include <hip/hip_runtime.h>
#include <math.h>

#define BATCH 8
#define CX 256
#define TC 512
#define CIN 768
#define HW_TOT 1024
#define NH 4
#define CHD 64

typedef __attribute__((ext_vector_type(8))) short short8;
typedef __attribute__((ext_vector_type(4))) short s4v;
typedef __attribute__((ext_vector_type(4))) float floatx4;

// round-to-nearest-even f32 -> bf16
static __device__ __forceinline__ short f2bf(float f) {
    union { float f; unsigned u; } c; c.f = f;
    unsigned r = (c.u + 0x7fffu + ((c.u >> 16) & 1u)) >> 16;
    return (short)r;
}

// ---------------------------------------------------------------------------
// Kernel 1a: per-(b,c) row partial sums over the 1024 spatial positions.
// One wave per row; coalesced float4; shuffle reduce. Grid 512 x 256.
// ---------------------------------------------------------------------------
__global__ __launch_bounds__(256)
void gn_part_kernel(const float* __restrict__ x,
                    float* __restrict__ psum, float* __restrict__ psumsq) {
    const int t = threadIdx.x;
    const int row = blockIdx.x * 4 + (t >> 6);   // b*256 + c, 2048 rows
    const int lane = t & 63;
    const float4* p = (const float4*)(x + (size_t)row * HW_TOT);
    float s = 0.f, ss = 0.f;
    #pragma unroll
    for (int i = 0; i < 4; i++) {
        float4 v = p[lane + 64 * i];
        s += v.x + v.y + v.z + v.w;
        ss += v.x * v.x + v.y * v.y + v.z * v.z + v.w * v.w;
    }
    #pragma unroll
    for (int d = 1; d < 64; d <<= 1) {
        s += __shfl_xor(s, d);
        ss += __shfl_xor(ss, d);
    }
    if (lane == 0) { psum[row] = s; psumsq[row] = ss; }
}

// ---------------------------------------------------------------------------
// Kernel 1b: finalize GroupNorm -> per-(b,c) scale/shift.
// Text channels are spatially broadcast: contribute 1024*v, 1024*v^2.
// Grid 256 (b*32+g) x 64.
// ---------------------------------------------------------------------------
__global__ __launch_bounds__(64)
void gn_fin_kernel(const float* __restrict__ psum, const float* __restrict__ psumsq,
                   const float* __restrict__ tf,
                   const float* __restrict__ gamma, const float* __restrict__ beta,
                   float* __restrict__ scale, float* __restrict__ shift) {
    const int b = blockIdx.x >> 5;
    const int g = blockIdx.x & 31;
    const int lane = threadIdx.x;
    const int cg = g * 24 + lane;
    float s = 0.f, ss = 0.f;
    if (lane < 24) {
        if (cg < CX) {
            s = psum[b * CX + cg];
            ss = psumsq[b * CX + cg];
        } else {
            float v = tf[b * TC + cg - CX];
            s = 1024.f * v;
            ss = 1024.f * v * v;
        }
    }
    #pragma unroll
    for (int d = 1; d < 64; d <<= 1) {
        s += __shfl_xor(s, d);
        ss += __shfl_xor(ss, d);
    }
    const float inv_n = 1.f / (24 * 1024);
    float mean = s * inv_n;
    float var = ss * inv_n - mean * mean;
    float rs = rsqrtf(var + 1e-6f);
    if (lane < 24) {
        float sc = gamma[cg] * rs;
        scale[b * CIN + cg] = sc;
        shift[b * CIN + cg] = beta[cg] - mean * sc;
    }
}

// ---------------------------------------------------------------------------
// Kernel 2: W -> Wt bf16 transposed: Wt[dg][c] = W_which[c][d], c<256 only.
// ---------------------------------------------------------------------------
__global__ __launch_bounds__(256)
void wt_kernel(const float* __restrict__ W0, const float* __restrict__ W1,
               const float* __restrict__ W2, short* __restrict__ Wt) {
    int dg = blockIdx.x * 256 + threadIdx.x;
    int which = dg >> 8, d = dg & 255;
    const float* Wm = (which == 0) ? W0 : (which == 1) ? W1 : W2;
    int c0base = blockIdx.y * 64;
    for (int c0 = c0base; c0 < c0base + 64; c0 += 8) {
        short8 o;
        #pragma unroll
        for (int i = 0; i < 8; i++) o[i] = f2bf(Wm[(size_t)(c0 + i) * CX + d]);
        *(short8*)(Wt + (size_t)dg * CX + c0) = o;
    }
}

// ---------------------------------------------------------------------------
// Kernel 3: hnT bf16 [b][hw][c<256] = normalize(x) transposed.
// ---------------------------------------------------------------------------
__global__ __launch_bounds__(256)
void hnt_kernel(const float* __restrict__ x, const float* __restrict__ scale,
                const float* __restrict__ shift, short* __restrict__ hnT) {
    int id = blockIdx.x * 256 + threadIdx.x;     // b*1024 + hw
    int b = id >> 10;
    const float* xb = x + (size_t)b * CX * HW_TOT + (id & 1023);
    const float* scb = scale + b * CIN;
    const float* shb = shift + b * CIN;
    short* outp = hnT + (size_t)id * CX;
    int c0base = blockIdx.y * 32;
    for (int c0 = c0base; c0 < c0base + 32; c0 += 8) {
        short8 o;
        #pragma unroll
        for (int i = 0; i < 8; i++) {
            float v = xb[(size_t)(c0 + i) * HW_TOT];
            o[i] = f2bf(v * scb[c0 + i] + shb[c0 + i]);
        }
        *(short8*)(outp + c0) = o;
    }
}

// ---------------------------------------------------------------------------
// Kernel 4: text contribution tc[b][dg] (per-batch constant, fp32 exact).
// ---------------------------------------------------------------------------
__global__ __launch_bounds__(256)
void text_kernel(const float* __restrict__ tf, const float* __restrict__ scale,
                 const float* __restrict__ shift,
                 const float* __restrict__ W0, const float* __restrict__ W1,
                 const float* __restrict__ W2, float* __restrict__ tc) {
    int b = blockIdx.x, dt = blockIdx.y;
    int which = dt >> 2, d0 = (dt & 3) * 64;
    const float* Wm = (which == 0) ? W0 : (which == 1) ? W1 : W2;
    __shared__ float hs[TC];
    __shared__ float red[4][64];
    int t = threadIdx.x;
    for (int c = t; c < TC; c += 256)
        hs[c] = tf[b * TC + c] * scale[b * CIN + CX + c] + shift[b * CIN + CX + c];
    __syncthreads();
    int td = t & 63, tq = t >> 6;
    float acc = 0.f;
    const float* wp = Wm + (size_t)(CX + tq * 128) * CX + d0 + td;
    for (int c = 0; c < 128; c++)
        acc = fmaf(hs[tq * 128 + c], wp[(size_t)c * CX], acc);
    red[tq][td] = acc;
    __syncthreads();
    if (t < 64)
        tc[b * CIN + which * CX + d0 + t] = red[0][t] + red[1][t] + red[2][t] + red[3][t];
}

// ---------------------------------------------------------------------------
// Kernel 5: MFMA QKV GEMM over spatial channels (K=256), bf16 in / fp32 acc.
// q,k written [b][hw][256]; v written [b][256][1024].
// ---------------------------------------------------------------------------
__global__ __launch_bounds__(256)
void qkv_gemm(const short* __restrict__ hnT, const short* __restrict__ Wt,
              const float* __restrict__ tc,
              const float* __restrict__ b0, const float* __restrict__ b1,
              const float* __restrict__ b2,
              short* __restrict__ qb, short* __restrict__ kb, short* __restrict__ vb) {
    const int hw0 = blockIdx.x * 128, dt = blockIdx.y, b = blockIdx.z;
    const int dg0 = dt * 128;
    const int which = dt >> 1;
    const bool OV = (which == 2);

    __shared__ short At[128 * 40];
    __shared__ short Bt[128 * 40];

    const int t = threadIdx.x;
    const int w = t >> 6, l = t & 63;
    const int wm = w >> 1, wn = w & 1;
    const int l15 = l & 15, q = l >> 4;

    const int srow = t >> 1, sch = (t & 1) * 16;
    const short* gA = hnT + (size_t)(b * HW_TOT + hw0 + srow) * CX + sch;
    const short* gB = Wt + (size_t)(dg0 + srow) * CX + sch;
    short* lA = At + srow * 40 + sch;
    short* lB = Bt + srow * 40 + sch;

    floatx4 acc[4][4] = {};
    for (int k0 = 0; k0 < CX; k0 += 32) {
        __syncthreads();
        *(short8*)lA       = *(const short8*)(gA + k0);
        *(short8*)(lA + 8) = *(const short8*)(gA + k0 + 8);
        *(short8*)lB       = *(const short8*)(gB + k0);
        *(short8*)(lB + 8) = *(const short8*)(gB + k0 + 8);
        __syncthreads();
        const short* aBase = OV ? Bt : At;
        const short* bBase = OV ? At : Bt;
        short8 af[4], bf[4];
        #pragma unroll
        for (int mt = 0; mt < 4; mt++)
            af[mt] = *(const short8*)(aBase + (wm * 64 + mt * 16 + l15) * 40 + q * 8);
        #pragma unroll
        for (int nt = 0; nt < 4; nt++)
            bf[nt] = *(const short8*)(bBase + (wn * 64 + nt * 16 + l15) * 40 + q * 8);
        #pragma unroll
        for (int mt = 0; mt < 4; mt++)
            #pragma unroll
            for (int nt = 0; nt < 4; nt++)
                acc[mt][nt] = __builtin_amdgcn_mfma_f32_16x16x32_bf16(
                    af[mt], bf[nt], acc[mt][nt], 0, 0, 0);
    }

    __syncthreads();
    const float* bias = (which == 0) ? b0 : (which == 1) ? b1 : b2;
    short* epi = At + w * (16 * 72);

    float colAdd[4];
    if (!OV) {
        #pragma unroll
        for (int nt = 0; nt < 4; nt++) {
            int cl = (dt & 1) * 128 + wn * 64 + l15 + nt * 16;
            colAdd[nt] = bias[cl] + tc[b * CIN + which * CX + cl];
        }
    }
    const int row_l = l >> 2, ch = l & 3;
    #pragma unroll
    for (int mt = 0; mt < 4; mt++) {
        #pragma unroll
        for (int rr = 0; rr < 4; rr++) {
            float radd = 0.f;
            if (OV) {
                int rl = (dt & 1) * 128 + wm * 64 + mt * 16 + q * 4 + rr;
                radd = bias[rl] + tc[b * CIN + 2 * CX + rl];
            }
            #pragma unroll
            for (int nt = 0; nt < 4; nt++) {
                float val = acc[mt][nt][rr] + (OV ? radd : colAdd[nt]);
                epi[(q * 4 + rr) * 72 + l15 + nt * 16] = f2bf(val);
            }
        }
        short8 v0 = *(const short8*)(epi + row_l * 72 + ch * 16);
        short8 v1 = *(const short8*)(epi + row_l * 72 + ch * 16 + 8);
        if (!OV) {
            short* outp = (which == 0) ? qb : kb;
            size_t off = (size_t)(b * HW_TOT + hw0 + wm * 64 + mt * 16 + row_l) * CX
                       + (dt & 1) * 128 + wn * 64 + ch * 16;
            *(short8*)(outp + off) = v0;
            *(short8*)(outp + off + 8) = v1;
        } else {
            size_t off = (size_t)(b * CX + (dt & 1) * 128 + wm * 64 + mt * 16 + row_l) * HW_TOT
                       + hw0 + wn * 64 + ch * 16;
            *(short8*)(vb + off) = v0;
            *(short8*)(vb + off + 8) = v1;
        }
    }
}

// ---------------------------------------------------------------------------
// Kernel 6: flash attention, S^T trick: MFMA(A=K,B=Q) puts qi on lane&15 so
// softmax rows are per-lane (2 shuffles) and exp'd P^T feeds the PV MFMA's
// B-operand DIRECTLY from registers (contraction order is a permutation:
// j<4 -> sacc[2kcc], j>=4 -> sacc[2kcc+1]). No P LDS round-trip.
// K/V staged with register prefetch. Grid (16,32) x 256.
// ---------------------------------------------------------------------------
__global__ __launch_bounds__(256)
void attn_kernel(const short* __restrict__ qb, const short* __restrict__ kb,
                 const short* __restrict__ vb, const float* __restrict__ x,
                 float* __restrict__ out) {
    const int qt = blockIdx.x, bh = blockIdx.y;
    const int b = bh >> 2, h = bh & 3;
    const int hw0 = qt * 64;

    __shared__ short Qs[64 * 72];
    __shared__ short Ks[64 * 72];
    __shared__ short Vs[64 * 72];

    const int t = threadIdx.x;
    const int w = t >> 6, l = t & 63;
    const int l15 = l & 15, q = l >> 4;
    const int srow = t >> 2, sch = (t & 3) * 16;

    // stage Q tile [qi][c]
    {
        const short* gq = qb + (size_t)(b * HW_TOT + hw0 + srow) * CX + h * CHD + sch;
        *(short8*)(Qs + srow * 72 + sch)     = *(const short8*)gq;
        *(short8*)(Qs + srow * 72 + sch + 8) = *(const short8*)(gq + 8);
    }

    // prefetch tile 0 into regs, store to LDS
    short8 pk0, pk1, pv0, pv1;
    {
        const short* gk = kb + (size_t)(b * HW_TOT + 0 + srow) * CX + h * CHD + sch;
        pk0 = *(const short8*)gk;
        pk1 = *(const short8*)(gk + 8);
        const short* gv = vb + (size_t)(b * CX + h * CHD + srow) * HW_TOT + 0 + sch;
        pv0 = *(const short8*)gv;
        pv1 = *(const short8*)(gv + 8);
        *(short8*)(Ks + srow * 72 + sch)     = pk0;
        *(short8*)(Ks + srow * 72 + sch + 8) = pk1;
        *(short8*)(Vs + srow * 72 + sch)     = pv0;
        *(short8*)(Vs + srow * 72 + sch + 8) = pv1;
    }
    __syncthreads();

    // Q fragment (B-operand): n=qi=w*16+l15, k=c
    const short8 aq0 = *(const short8*)(Qs + (w * 16 + l15) * 72 + q * 8);
    const short8 aq1 = *(const short8*)(Qs + (w * 16 + l15) * 72 + 32 + q * 8);

    floatx4 oacc[4] = {};
    float mrow = -1e30f, lrow = 0.f;

    for (int j = 0; j < 16; j++) {
        if (j < 15) {
            const int j0 = (j + 1) * 64;
            const short* gk = kb + (size_t)(b * HW_TOT + j0 + srow) * CX + h * CHD + sch;
            pk0 = *(const short8*)gk;
            pk1 = *(const short8*)(gk + 8);
            const short* gv = vb + (size_t)(b * CX + h * CHD + srow) * HW_TOT + j0 + sch;
            pv0 = *(const short8*)gv;
            pv1 = *(const short8*)(gv + 8);
        }

        // S^T = K . Q^T : C[m=kj][n=qi]
        floatx4 sacc[4] = {};
        #pragma unroll
        for (int nt = 0; nt < 4; nt++) {
            short8 kf0 = *(const short8*)(Ks + (nt * 16 + l15) * 72 + q * 8);
            short8 kf1 = *(const short8*)(Ks + (nt * 16 + l15) * 72 + 32 + q * 8);
            sacc[nt] = __builtin_amdgcn_mfma_f32_16x16x32_bf16(kf0, aq0, sacc[nt], 0, 0, 0);
            sacc[nt] = __builtin_amdgcn_mfma_f32_16x16x32_bf16(kf1, aq1, sacc[nt], 0, 0, 0);
        }

        // online softmax: this lane owns row qi = w*16+l15 (kj spread over quads)
        float tv[4][4];
        float mx = -1e30f;
        #pragma unroll
        for (int nt = 0; nt < 4; nt++)
            #pragma unroll
            for (int r = 0; r < 4; r++) {
                tv[nt][r] = sacc[nt][r] * 0.125f;
                mx = fmaxf(mx, tv[nt][r]);
            }
        mx = fmaxf(mx, __shfl_xor(mx, 16));
        mx = fmaxf(mx, __shfl_xor(mx, 32));
        float mn = fmaxf(mrow, mx);
        float al = __expf(mrow - mn);
        float rs = 0.f;
        short8 pf[2];
        #pragma unroll
        for (int nt = 0; nt < 4; nt++)
            #pragma unroll
            for (int r = 0; r < 4; r++) {
                float e = __expf(tv[nt][r] - mn);
                rs += e;
                pf[nt >> 1][(nt & 1) * 4 + r] = f2bf(e);
            }
        rs += __shfl_xor(rs, 16);
        rs += __shfl_xor(rs, 32);
        lrow = lrow * al + rs;
        mrow = mn;
        #pragma unroll
        for (int ct = 0; ct < 4; ct++)
            #pragma unroll
            for (int r = 0; r < 4; r++) oacc[ct][r] *= al;

        // O^T += V^T . P : C[m=c][n=qi]; contraction permuted so pf feeds B
        #pragma unroll
        for (int ct = 0; ct < 4; ct++) {
            const short* vr = Vs + (ct * 16 + l15) * 72;
            #pragma unroll
            for (int kcc = 0; kcc < 2; kcc++) {
                s4v vlo = *(const s4v*)(vr + kcc * 32 + q * 4);
                s4v vhi = *(const s4v*)(vr + kcc * 32 + 16 + q * 4);
                short8 vf = __builtin_shufflevector(vlo, vhi, 0, 1, 2, 3, 4, 5, 6, 7);
                oacc[ct] = __builtin_amdgcn_mfma_f32_16x16x32_bf16(vf, pf[kcc], oacc[ct], 0, 0, 0);
            }
        }

        __syncthreads();
        if (j < 15) {
            *(short8*)(Ks + srow * 72 + sch)     = pk0;
            *(short8*)(Ks + srow * 72 + sch + 8) = pk1;
            *(short8*)(Vs + srow * 72 + sch)     = pv0;
            *(short8*)(Vs + srow * 72 + sch + 8) = pv1;
        }
        __syncthreads();
    }

    // epilogue: lane holds O^T[c = ct*16+q*4+r][qi = w*16+l15]
    const float rinv = 1.f / lrow;
    #pragma unroll
    for (int ct = 0; ct < 4; ct++)
        #pragma unroll
        for (int r = 0; r < 4; r++) {
            int c = h * CHD + ct * 16 + q * 4 + r;
            size_t idx = (size_t)(b * CX + c) * HW_TOT + hw0 + w * 16 + l15;
            out[idx] = x[idx] + oacc[ct][r] * rinv;
        }
}

// ---------------------------------------------------------------------------
extern "C" void kernel_launch(void* const* d_in, const int* in_sizes, int n_in,
                              void* d_out, int out_size, void* d_ws, size_t ws_size,
                              hipStream_t stream) {
    (void)in_sizes; (void)n_in; (void)out_size; (void)ws_size;
    const float* x     = (const float*)d_in[0];
    const float* tf    = (const float*)d_in[1];
    const float* gamma = (const float*)d_in[2];
    const float* beta  = (const float*)d_in[3];
    const float* W0 = (const float*)d_in[4];
    const float* b0 = (const float*)d_in[5];
    const float* W1 = (const float*)d_in[6];
    const float* b1 = (const float*)d_in[7];
    const float* W2 = (const float*)d_in[8];
    const float* b2 = (const float*)d_in[9];

    char* ws = (char*)d_ws;
    float* scale  = (float*)(ws);                 // 24576 B
    float* shift  = (float*)(ws + 24576);         // 24576 B
    float* tcb    = (float*)(ws + 49152);         // 24576 B
    short* Wt     = (short*)(ws + 73728);         // 393216 B
    short* hnT    = (short*)(ws + 466944);        // 4 MiB
    short* qb     = (short*)(ws + 4661248);       // 4 MiB
    short* kb     = (short*)(ws + 8855552);       // 4 MiB
    short* vb     = (short*)(ws + 13049856);      // 4 MiB
    float* psum   = (float*)(ws + 17244160);      // 8192 B
    float* psumsq = (float*)(ws + 17252352);      // 8192 B

    hipLaunchKernelGGL(gn_part_kernel, dim3(512), dim3(256), 0, stream, x, psum, psumsq);
    hipLaunchKernelGGL(gn_fin_kernel, dim3(256), dim3(64), 0, stream,
                       psum, psumsq, tf, gamma, beta, scale, shift);
    hipLaunchKernelGGL(wt_kernel, dim3(3, 4), dim3(256), 0, stream, W0, W1, W2, Wt);
    hipLaunchKernelGGL(hnt_kernel, dim3(32, 8), dim3(256), 0, stream, x, scale, shift, hnT);
    hipLaunchKernelGGL(text_kernel, dim3(BATCH, 12), dim3(256), 0, stream,
                       tf, scale, shift, W0, W1, W2, tcb);
    hipLaunchKernelGGL(qkv_gemm, dim3(8, 6, BATCH), dim3(256), 0, stream,
                       hnT, Wt, tcb, b0, b1, b2, qb, kb, vb);
    hipLaunchKernelGGL(attn_kernel, dim3(16, 32), dim3(256), 0, stream,
                       qb, kb, vb, x, (float*)d_out);
}

// Round 5
// 128.193 us; speedup vs baseline: 3.1680x; 1.0569x over previous
//
#include <hip/hip_runtime.h>
#include <math.h>

#define BATCH 8
#define CX 256
#define TC 512
#define CIN 768
#define HW_TOT 1024
#define NH 4
#define CHD 64

typedef __attribute__((ext_vector_type(8))) short short8;
typedef __attribute__((ext_vector_type(4))) short s4v;
typedef __attribute__((ext_vector_type(4))) float floatx4;

// round-to-nearest-even f32 -> bf16
static __device__ __forceinline__ short f2bf(float f) {
    union { float f; unsigned u; } c; c.f = f;
    unsigned r = (c.u + 0x7fffu + ((c.u >> 16) & 1u)) >> 16;
    return (short)r;
}

// ---------------------------------------------------------------------------
// Kernel 1a: per-(b,c) row partial sums. One wave per row. Grid 512 x 256.
// ---------------------------------------------------------------------------
__global__ __launch_bounds__(256)
void gn_part_kernel(const float* __restrict__ x,
                    float* __restrict__ psum, float* __restrict__ psumsq) {
    const int t = threadIdx.x;
    const int row = blockIdx.x * 4 + (t >> 6);
    const int lane = t & 63;
    const float4* p = (const float4*)(x + (size_t)row * HW_TOT);
    float s = 0.f, ss = 0.f;
    #pragma unroll
    for (int i = 0; i < 4; i++) {
        float4 v = p[lane + 64 * i];
        s += v.x + v.y + v.z + v.w;
        ss += v.x * v.x + v.y * v.y + v.z * v.z + v.w * v.w;
    }
    #pragma unroll
    for (int d = 1; d < 64; d <<= 1) {
        s += __shfl_xor(s, d);
        ss += __shfl_xor(ss, d);
    }
    if (lane == 0) { psum[row] = s; psumsq[row] = ss; }
}

// ---------------------------------------------------------------------------
// Kernel 1b: finalize GroupNorm -> scale/shift. Grid 256 x 64.
// ---------------------------------------------------------------------------
__global__ __launch_bounds__(64)
void gn_fin_kernel(const float* __restrict__ psum, const float* __restrict__ psumsq,
                   const float* __restrict__ tf,
                   const float* __restrict__ gamma, const float* __restrict__ beta,
                   float* __restrict__ scale, float* __restrict__ shift) {
    const int b = blockIdx.x >> 5;
    const int g = blockIdx.x & 31;
    const int lane = threadIdx.x;
    const int cg = g * 24 + lane;
    float s = 0.f, ss = 0.f;
    if (lane < 24) {
        if (cg < CX) {
            s = psum[b * CX + cg];
            ss = psumsq[b * CX + cg];
        } else {
            float v = tf[b * TC + cg - CX];
            s = 1024.f * v;
            ss = 1024.f * v * v;
        }
    }
    #pragma unroll
    for (int d = 1; d < 64; d <<= 1) {
        s += __shfl_xor(s, d);
        ss += __shfl_xor(ss, d);
    }
    const float inv_n = 1.f / (24 * 1024);
    float mean = s * inv_n;
    float var = ss * inv_n - mean * mean;
    float rs = rsqrtf(var + 1e-6f);
    if (lane < 24) {
        float sc = gamma[cg] * rs;
        scale[b * CIN + cg] = sc;
        shift[b * CIN + cg] = beta[cg] - mean * sc;
    }
}

// ---------------------------------------------------------------------------
// Kernel 2: merged prep: hnT transpose (blocks 0-255), W transpose (256-267),
// text contribution (268-363). Shared arrays hoisted to kernel scope.
// ---------------------------------------------------------------------------
__global__ __launch_bounds__(256)
void prep_kernel(const float* __restrict__ x, const float* __restrict__ tf,
                 const float* __restrict__ scale, const float* __restrict__ shift,
                 const float* __restrict__ W0, const float* __restrict__ W1,
                 const float* __restrict__ W2,
                 short* __restrict__ hnT, short* __restrict__ Wt,
                 float* __restrict__ tc) {
    __shared__ float hs[TC];
    __shared__ float red[4][64];
    const int bx = blockIdx.x;
    const int t = threadIdx.x;
    if (bx < 256) {
        // hnT bf16 [b][hw][c<256]
        int id = (bx & 31) * 256 + t;
        int b = id >> 10;
        const float* xb = x + (size_t)b * CX * HW_TOT + (id & 1023);
        const float* scb = scale + b * CIN;
        const float* shb = shift + b * CIN;
        short* outp = hnT + (size_t)id * CX;
        int c0base = (bx >> 5) * 32;
        for (int c0 = c0base; c0 < c0base + 32; c0 += 8) {
            short8 o;
            #pragma unroll
            for (int i = 0; i < 8; i++) {
                float v = xb[(size_t)(c0 + i) * HW_TOT];
                o[i] = f2bf(v * scb[c0 + i] + shb[c0 + i]);
            }
            *(short8*)(outp + c0) = o;
        }
    } else if (bx < 268) {
        // Wt[dg][c] = W_which[c][d], c<256
        int m = bx - 256;
        int dg = (m % 3) * 256 + t;
        int which = dg >> 8, d = dg & 255;
        const float* Wm = (which == 0) ? W0 : (which == 1) ? W1 : W2;
        int c0base = (m / 3) * 64;
        for (int c0 = c0base; c0 < c0base + 64; c0 += 8) {
            short8 o;
            #pragma unroll
            for (int i = 0; i < 8; i++) o[i] = f2bf(Wm[(size_t)(c0 + i) * CX + d]);
            *(short8*)(Wt + (size_t)dg * CX + c0) = o;
        }
    } else {
        // text contribution tc[b][dg] (fp32 exact)
        int m = bx - 268;
        int b = m & 7, dt = m >> 3;
        int which = dt >> 2, d0 = (dt & 3) * 64;
        const float* Wm = (which == 0) ? W0 : (which == 1) ? W1 : W2;
        for (int c = t; c < TC; c += 256)
            hs[c] = tf[b * TC + c] * scale[b * CIN + CX + c] + shift[b * CIN + CX + c];
        __syncthreads();
        int td = t & 63, tq = t >> 6;
        float acc = 0.f;
        const float* wp = Wm + (size_t)(CX + tq * 128) * CX + d0 + td;
        for (int c = 0; c < 128; c++)
            acc = fmaf(hs[tq * 128 + c], wp[(size_t)c * CX], acc);
        red[tq][td] = acc;
        __syncthreads();
        if (t < 64)
            tc[b * CIN + which * CX + d0 + t] = red[0][t] + red[1][t] + red[2][t] + red[3][t];
    }
}

// ---------------------------------------------------------------------------
// Kernel 3: MFMA QKV GEMM (K=256), bf16 in / fp32 acc. (unchanged, proven)
// q,k written [b][hw][256]; v written [b][256][1024].
// ---------------------------------------------------------------------------
__global__ __launch_bounds__(256)
void qkv_gemm(const short* __restrict__ hnT, const short* __restrict__ Wt,
              const float* __restrict__ tc,
              const float* __restrict__ b0, const float* __restrict__ b1,
              const float* __restrict__ b2,
              short* __restrict__ qb, short* __restrict__ kb, short* __restrict__ vb) {
    const int hw0 = blockIdx.x * 128, dt = blockIdx.y, b = blockIdx.z;
    const int dg0 = dt * 128;
    const int which = dt >> 1;
    const bool OV = (which == 2);

    __shared__ short At[128 * 40];
    __shared__ short Bt[128 * 40];

    const int t = threadIdx.x;
    const int w = t >> 6, l = t & 63;
    const int wm = w >> 1, wn = w & 1;
    const int l15 = l & 15, q = l >> 4;

    const int srow = t >> 1, sch = (t & 1) * 16;
    const short* gA = hnT + (size_t)(b * HW_TOT + hw0 + srow) * CX + sch;
    const short* gB = Wt + (size_t)(dg0 + srow) * CX + sch;
    short* lA = At + srow * 40 + sch;
    short* lB = Bt + srow * 40 + sch;

    floatx4 acc[4][4] = {};
    for (int k0 = 0; k0 < CX; k0 += 32) {
        __syncthreads();
        *(short8*)lA       = *(const short8*)(gA + k0);
        *(short8*)(lA + 8) = *(const short8*)(gA + k0 + 8);
        *(short8*)lB       = *(const short8*)(gB + k0);
        *(short8*)(lB + 8) = *(const short8*)(gB + k0 + 8);
        __syncthreads();
        const short* aBase = OV ? Bt : At;
        const short* bBase = OV ? At : Bt;
        short8 af[4], bf[4];
        #pragma unroll
        for (int mt = 0; mt < 4; mt++)
            af[mt] = *(const short8*)(aBase + (wm * 64 + mt * 16 + l15) * 40 + q * 8);
        #pragma unroll
        for (int nt = 0; nt < 4; nt++)
            bf[nt] = *(const short8*)(bBase + (wn * 64 + nt * 16 + l15) * 40 + q * 8);
        #pragma unroll
        for (int mt = 0; mt < 4; mt++)
            #pragma unroll
            for (int nt = 0; nt < 4; nt++)
                acc[mt][nt] = __builtin_amdgcn_mfma_f32_16x16x32_bf16(
                    af[mt], bf[nt], acc[mt][nt], 0, 0, 0);
    }

    __syncthreads();
    const float* bias = (which == 0) ? b0 : (which == 1) ? b1 : b2;
    short* epi = At + w * (16 * 72);

    float colAdd[4];
    if (!OV) {
        #pragma unroll
        for (int nt = 0; nt < 4; nt++) {
            int cl = (dt & 1) * 128 + wn * 64 + l15 + nt * 16;
            colAdd[nt] = bias[cl] + tc[b * CIN + which * CX + cl];
        }
    }
    const int row_l = l >> 2, ch = l & 3;
    #pragma unroll
    for (int mt = 0; mt < 4; mt++) {
        #pragma unroll
        for (int rr = 0; rr < 4; rr++) {
            float radd = 0.f;
            if (OV) {
                int rl = (dt & 1) * 128 + wm * 64 + mt * 16 + q * 4 + rr;
                radd = bias[rl] + tc[b * CIN + 2 * CX + rl];
            }
            #pragma unroll
            for (int nt = 0; nt < 4; nt++) {
                float val = acc[mt][nt][rr] + (OV ? radd : colAdd[nt]);
                epi[(q * 4 + rr) * 72 + l15 + nt * 16] = f2bf(val);
            }
        }
        short8 v0 = *(const short8*)(epi + row_l * 72 + ch * 16);
        short8 v1 = *(const short8*)(epi + row_l * 72 + ch * 16 + 8);
        if (!OV) {
            short* outp = (which == 0) ? qb : kb;
            size_t off = (size_t)(b * HW_TOT + hw0 + wm * 64 + mt * 16 + row_l) * CX
                       + (dt & 1) * 128 + wn * 64 + ch * 16;
            *(short8*)(outp + off) = v0;
            *(short8*)(outp + off + 8) = v1;
        } else {
            size_t off = (size_t)(b * CX + (dt & 1) * 128 + wm * 64 + mt * 16 + row_l) * HW_TOT
                       + hw0 + wn * 64 + ch * 16;
            *(short8*)(vb + off) = v0;
            *(short8*)(vb + off + 8) = v1;
        }
    }
}

// ---------------------------------------------------------------------------
// Kernel 4: split-j flash attention partial. Fixed-max softmax (exact:
// softmax invariant to constant shift; |logits| << 87 so fp32 exp is safe).
// Each block does 8 of 16 key tiles; partial o (unnormalized, C-layout) and
// partial l go to split-private buffers. V layout / frag reads are the
// r3-proven pattern. Grid (16 qt, 32 bh, 2 split) x 256.
// ---------------------------------------------------------------------------
__global__ __launch_bounds__(256)
void attn_part(const short* __restrict__ qb, const short* __restrict__ kb,
               const short* __restrict__ vb,
               float* __restrict__ opart, float* __restrict__ lpart) {
    const int qt = blockIdx.x, bh = blockIdx.y, sp = blockIdx.z;
    const int b = bh >> 2, h = bh & 3;
    const int hw0 = qt * 64;

    __shared__ short Qs[64 * 72];
    __shared__ short Ks[64 * 72];
    __shared__ short Vs[64 * 72];

    const int t = threadIdx.x;
    const int w = t >> 6, l = t & 63;
    const int l15 = l & 15, q = l >> 4;
    const int srow = t >> 2, sch = (t & 3) * 16;

    {   // stage Q tile [qi][c]
        const short* gq = qb + (size_t)(b * HW_TOT + hw0 + srow) * CX + h * CHD + sch;
        *(short8*)(Qs + srow * 72 + sch)     = *(const short8*)gq;
        *(short8*)(Qs + srow * 72 + sch + 8) = *(const short8*)(gq + 8);
    }

    // prefetch first tile of this split
    short8 pk0, pk1, pv0, pv1;
    {
        const int j0 = sp * 512;
        const short* gk = kb + (size_t)(b * HW_TOT + j0 + srow) * CX + h * CHD + sch;
        pk0 = *(const short8*)gk;
        pk1 = *(const short8*)(gk + 8);
        const short* gv = vb + (size_t)(b * CX + h * CHD + srow) * HW_TOT + j0 + sch;
        pv0 = *(const short8*)gv;
        pv1 = *(const short8*)(gv + 8);
    }
    __syncthreads();
    const short8 aq0 = *(const short8*)(Qs + (w * 16 + l15) * 72 + q * 8);
    const short8 aq1 = *(const short8*)(Qs + (w * 16 + l15) * 72 + 32 + q * 8);

    floatx4 oacc[4] = {};
    float lsum = 0.f;

    for (int jj = 0; jj < 8; jj++) {
        // write prefetched tile into LDS (K and V natural [row][16ch] layout)
        *(short8*)(Ks + srow * 72 + sch)     = pk0;
        *(short8*)(Ks + srow * 72 + sch + 8) = pk1;
        *(short8*)(Vs + srow * 72 + sch)     = pv0;
        *(short8*)(Vs + srow * 72 + sch + 8) = pv1;
        __syncthreads();

        if (jj < 7) {
            const int j0 = sp * 512 + (jj + 1) * 64;
            const short* gk = kb + (size_t)(b * HW_TOT + j0 + srow) * CX + h * CHD + sch;
            pk0 = *(const short8*)gk;
            pk1 = *(const short8*)(gk + 8);
            const short* gv = vb + (size_t)(b * CX + h * CHD + srow) * HW_TOT + j0 + sch;
            pv0 = *(const short8*)gv;
            pv1 = *(const short8*)(gv + 8);
        }

        // S^T = K . Q^T : C[m=kj][n=qi]
        floatx4 sacc[4] = {};
        #pragma unroll
        for (int nt = 0; nt < 4; nt++) {
            short8 kf0 = *(const short8*)(Ks + (nt * 16 + l15) * 72 + q * 8);
            short8 kf1 = *(const short8*)(Ks + (nt * 16 + l15) * 72 + 32 + q * 8);
            sacc[nt] = __builtin_amdgcn_mfma_f32_16x16x32_bf16(kf0, aq0, sacc[nt], 0, 0, 0);
            sacc[nt] = __builtin_amdgcn_mfma_f32_16x16x32_bf16(kf1, aq1, sacc[nt], 0, 0, 0);
        }

        // fixed-max softmax: p = exp(s*0.125 - 10); accumulate per-lane l
        short8 pf[2];
        #pragma unroll
        for (int nt = 0; nt < 4; nt++)
            #pragma unroll
            for (int r = 0; r < 4; r++) {
                float e = __expf(fmaf(sacc[nt][r], 0.125f, -10.f));
                lsum += e;
                pf[nt >> 1][(nt & 1) * 4 + r] = f2bf(e);
            }

        // O^T += V^T . P : A=V (r3-proven concat reads), B=P from registers
        #pragma unroll
        for (int ct = 0; ct < 4; ct++) {
            const short* vr = Vs + (ct * 16 + l15) * 72;
            #pragma unroll
            for (int kcc = 0; kcc < 2; kcc++) {
                s4v vlo = *(const s4v*)(vr + kcc * 32 + q * 4);
                s4v vhi = *(const s4v*)(vr + kcc * 32 + 16 + q * 4);
                short8 vf = __builtin_shufflevector(vlo, vhi, 0, 1, 2, 3, 4, 5, 6, 7);
                oacc[ct] = __builtin_amdgcn_mfma_f32_16x16x32_bf16(vf, pf[kcc], oacc[ct], 0, 0, 0);
            }
        }
        __syncthreads();   // all LDS reads done before next iter's writes
    }

    // write partial o (C-layout, coalesced over qi) and partial l
    float* op = opart + ((size_t)(sp * BATCH + b) * CX) * HW_TOT;
    #pragma unroll
    for (int ct = 0; ct < 4; ct++)
        #pragma unroll
        for (int r = 0; r < 4; r++) {
            int c = h * CHD + ct * 16 + q * 4 + r;
            op[(size_t)c * HW_TOT + hw0 + w * 16 + l15] = oacc[ct][r];
        }
    lsum += __shfl_xor(lsum, 16);
    lsum += __shfl_xor(lsum, 32);
    if (q == 0)
        lpart[(size_t)(sp * 32 + bh) * HW_TOT + hw0 + w * 16 + l15] = lsum;
}

// ---------------------------------------------------------------------------
// Kernel 5: combine split partials + residual. Grid 2048 x 256, float4.
// ---------------------------------------------------------------------------
__global__ __launch_bounds__(256)
void attn_epi(const float* __restrict__ opart, const float* __restrict__ lpart,
              const float* __restrict__ x, float* __restrict__ out) {
    const int idx = (blockIdx.x * 256 + threadIdx.x) * 4;   // [b][c][hw]
    const int b = idx >> 18, c = (idx >> 10) & 255, hw = idx & 1023;
    const int bh = b * 4 + (c >> 6);
    const size_t lo = (size_t)bh * HW_TOT + hw;
    float4 l0 = *(const float4*)(lpart + lo);
    float4 l1 = *(const float4*)(lpart + 32 * HW_TOT + lo);
    float4 o0 = *(const float4*)(opart + idx);
    float4 o1 = *(const float4*)(opart + BATCH * CX * HW_TOT + idx);
    float4 xv = *(const float4*)(x + idx);
    float4 ov;
    ov.x = xv.x + (o0.x + o1.x) / (l0.x + l1.x);
    ov.y = xv.y + (o0.y + o1.y) / (l0.y + l1.y);
    ov.z = xv.z + (o0.z + o1.z) / (l0.z + l1.z);
    ov.w = xv.w + (o0.w + o1.w) / (l0.w + l1.w);
    *(float4*)(out + idx) = ov;
}

// ---------------------------------------------------------------------------
extern "C" void kernel_launch(void* const* d_in, const int* in_sizes, int n_in,
                              void* d_out, int out_size, void* d_ws, size_t ws_size,
                              hipStream_t stream) {
    (void)in_sizes; (void)n_in; (void)out_size; (void)ws_size;
    const float* x     = (const float*)d_in[0];
    const float* tf    = (const float*)d_in[1];
    const float* gamma = (const float*)d_in[2];
    const float* beta  = (const float*)d_in[3];
    const float* W0 = (const float*)d_in[4];
    const float* b0 = (const float*)d_in[5];
    const float* W1 = (const float*)d_in[6];
    const float* b1 = (const float*)d_in[7];
    const float* W2 = (const float*)d_in[8];
    const float* b2 = (const float*)d_in[9];

    char* ws = (char*)d_ws;
    float* scale  = (float*)(ws);                 // 24576 B
    float* shift  = (float*)(ws + 24576);         // 24576 B
    float* tcb    = (float*)(ws + 49152);         // 24576 B
    short* Wt     = (short*)(ws + 73728);         // 393216 B
    short* hnT    = (short*)(ws + 466944);        // 4 MiB
    short* qb     = (short*)(ws + 4661248);       // 4 MiB
    short* kb     = (short*)(ws + 8855552);       // 4 MiB
    short* vb     = (short*)(ws + 13049856);      // 4 MiB
    float* psum   = (float*)(ws + 17244160);      // 8 KiB
    float* psumsq = (float*)(ws + 17252352);      // 8 KiB
    float* opart  = (float*)(ws + 17260544);      // 16 MiB (2 splits)
    float* lpart  = (float*)(ws + 34037760);      // 256 KiB (2 splits)

    hipLaunchKernelGGL(gn_part_kernel, dim3(512), dim3(256), 0, stream, x, psum, psumsq);
    hipLaunchKernelGGL(gn_fin_kernel, dim3(256), dim3(64), 0, stream,
                       psum, psumsq, tf, gamma, beta, scale, shift);
    hipLaunchKernelGGL(prep_kernel, dim3(364), dim3(256), 0, stream,
                       x, tf, scale, shift, W0, W1, W2, hnT, Wt, tcb);
    hipLaunchKernelGGL(qkv_gemm, dim3(8, 6, BATCH), dim3(256), 0, stream,
                       hnT, Wt, tcb, b0, b1, b2, qb, kb, vb);
    hipLaunchKernelGGL(attn_part, dim3(16, 32, 2), dim3(256), 0, stream,
                       qb, kb, vb, opart, lpart);
    hipLaunchKernelGGL(attn_epi, dim3(2048), dim3(256), 0, stream,
                       opart, lpart, x, (float*)d_out);
}